// Round 2
// baseline (372.011 us; speedup 1.0000x reference)
//
#include <hip/hip_runtime.h>
#include <cstdint>
#include <cstddef>

#define B_DIM 512
#define T_DIM 200
#define D_DIM 512
#define NPAD  208   // N padded to 13*16
#define NKG   28    // K padded to 224 = 28 groups of 8
#define NT    13    // n-tiles of 16
#define DT    128   // d rows per block
#define KS_STEPS 7  // 224 / 32

typedef short  short8  __attribute__((ext_vector_type(8)));
typedef float  floatx4 __attribute__((ext_vector_type(4)));

__device__ __forceinline__ unsigned short f2bf(float f) {
  unsigned int u = __float_as_uint(f);
  u += 0x7fffu + ((u >> 16) & 1u);   // round-to-nearest-even
  return (unsigned short)(u >> 16);
}
__device__ __forceinline__ float bf2f(unsigned short h) {
  return __uint_as_float(((unsigned int)h) << 16);
}

// W (200x200 fp32) -> bf16, padded 224x208, B-fragment layout [k/8][n][k%8]
__global__ void prep_w_kernel(const float* __restrict__ W,
                              unsigned short* __restrict__ wf) {
  int idx = blockIdx.x * blockDim.x + threadIdx.x;
  if (idx >= NKG * 8 * NPAD) return;
  int k = idx / NPAD;
  int n = idx - k * NPAD;
  float v = (k < T_DIM && n < T_DIM) ? W[k * T_DIM + n] : 0.0f;
  wf[((size_t)(k >> 3) * NPAD + n) * 8 + (k & 7)] = f2bf(v);
}

__global__ __launch_bounds__(256, 2)
void attn_kernel(const float* __restrict__ X,
                 const unsigned short* __restrict__ wf,
                 const float* __restrict__ bias,
                 float* __restrict__ out) {
  // X tile in bf16, A-fragment layout [k/8][m][k%8]: 28*128*8*2B = 56 KiB
  __shared__ unsigned short Xa[NKG * DT * 8];

  const int tid = threadIdx.x;
  const int bb  = blockIdx.x >> 2;
  const int d0  = (blockIdx.x & 3) * DT;

  // ---- stage X tile: global fp32 (coalesced over d=m) -> LDS bf16 frag layout
  {
    const int m    = tid & (DT - 1);
    const int half = tid >> 7;
    for (int kk = half; kk < NKG; kk += 2) {
      unsigned short pk[8];
      if (kk < 25) {  // T=200 = 25*8 exactly; kk>=25 is zero padding
        const float* g = X + ((size_t)bb * T_DIM + (size_t)kk * 8) * D_DIM + d0 + m;
        #pragma unroll
        for (int j = 0; j < 8; ++j) pk[j] = f2bf(g[(size_t)j * D_DIM]);
      } else {
        #pragma unroll
        for (int j = 0; j < 8; ++j) pk[j] = 0;
      }
      int4 w;
      w.x = (int)pk[0] | ((int)pk[1] << 16);
      w.y = (int)pk[2] | ((int)pk[3] << 16);
      w.z = (int)pk[4] | ((int)pk[5] << 16);
      w.w = (int)pk[6] | ((int)pk[7] << 16);
      *(int4*)(&Xa[(kk * DT + m) * 8]) = w;  // ds_write_b128
    }
  }
  __syncthreads();

  const int lane = tid & 63;
  const int l15  = lane & 15;
  const int g    = lane >> 4;
  const int wv   = tid >> 6;
  const int mt0  = wv * 2;   // each wave owns m-tiles mt0, mt0+1 (32 d-rows)

  float bv[NT];
  #pragma unroll
  for (int nt = 0; nt < NT; ++nt) {
    int n = nt * 16 + l15;
    bv[nt] = (n < T_DIM) ? bias[n] : 0.0f;
  }

  floatx4 acc[2][NT];
  #pragma unroll
  for (int mt = 0; mt < 2; ++mt)
    #pragma unroll
    for (int nt = 0; nt < NT; ++nt)
      acc[mt][nt] = (floatx4){0.f, 0.f, 0.f, 0.f};

  // ---- K-loop: no barriers, compiler free to pipeline global B-frag loads
  for (int ks = 0; ks < KS_STEPS; ++ks) {
    const int kg = ks * 4 + g;
    short8 a0 = *(const short8*)(&Xa[(kg * DT + mt0 * 16 + l15) * 8]);
    short8 a1 = *(const short8*)(&Xa[(kg * DT + mt0 * 16 + 16 + l15) * 8]);
    const unsigned short* wp = wf + ((size_t)kg * NPAD + l15) * 8;
    #pragma unroll
    for (int nt = 0; nt < NT; ++nt) {
      short8 bfr = *(const short8*)(wp + nt * 16 * 8);
      acc[0][nt] = __builtin_amdgcn_mfma_f32_16x16x32_bf16(a0, bfr, acc[0][nt], 0, 0, 0);
      acc[1][nt] = __builtin_amdgcn_mfma_f32_16x16x32_bf16(a1, bfr, acc[1][nt], 0, 0, 0);
    }
  }

  // ---- epilogue: tanh -> softmax over n (row-wise) -> dot with x over t
  // C/D layout: col = lane&15 (n), row = g*4 + reg (m within tile)
  #pragma unroll
  for (int mt = 0; mt < 2; ++mt) {
    const int mtile = mt0 + mt;      // ABSOLUTE m-tile (bug fix vs R1)
    float sc[NT][4];
    float rmax[4] = {-3.0e38f, -3.0e38f, -3.0e38f, -3.0e38f};
    #pragma unroll
    for (int nt = 0; nt < NT; ++nt) {
      const int n = nt * 16 + l15;
      const bool valid = (n < T_DIM);
      #pragma unroll
      for (int r = 0; r < 4; ++r) {
        float s;
        if (valid) {
          float z = acc[mt][nt][r] + bv[nt];
          float e = __expf(2.0f * z);            // tanh = 1 - 2/(e^{2z}+1)
          s = 1.0f - __fdividef(2.0f, e + 1.0f); // saturates correctly at +/-inf
        } else {
          s = -1.0e30f;
        }
        sc[nt][r] = s;
        rmax[r] = fmaxf(rmax[r], s);
      }
    }
    #pragma unroll
    for (int off = 1; off <= 8; off <<= 1)
      #pragma unroll
      for (int r = 0; r < 4; ++r)
        rmax[r] = fmaxf(rmax[r], __shfl_xor(rmax[r], off, 64));

    float rsum[4] = {0.f, 0.f, 0.f, 0.f};
    #pragma unroll
    for (int nt = 0; nt < NT; ++nt)
      #pragma unroll
      for (int r = 0; r < 4; ++r) {
        float p = __expf(sc[nt][r] - rmax[r]);   // masked cols -> exp(-1e30)=0
        sc[nt][r] = p;
        rsum[r] += p;
      }
    #pragma unroll
    for (int off = 1; off <= 8; off <<= 1)
      #pragma unroll
      for (int r = 0; r < 4; ++r)
        rsum[r] += __shfl_xor(rsum[r], off, 64);

    float part[4] = {0.f, 0.f, 0.f, 0.f};
    #pragma unroll
    for (int nt = 0; nt < NT; ++nt) {
      const int t = nt * 16 + l15;               // t < 208 < 224, pad region is zeros
      const unsigned short* xp = &Xa[((t >> 3) * DT) * 8 + (t & 7)];
      #pragma unroll
      for (int r = 0; r < 4; ++r) {
        const int m = mtile * 16 + g * 4 + r;
        part[r] += sc[nt][r] * bf2f(xp[m * 8]);  // X[t][d0+m]
      }
    }
    #pragma unroll
    for (int off = 1; off <= 8; off <<= 1)
      #pragma unroll
      for (int r = 0; r < 4; ++r)
        part[r] += __shfl_xor(part[r], off, 64);

    if (l15 == 0) {
      #pragma unroll
      for (int r = 0; r < 4; ++r)
        out[(size_t)bb * D_DIM + d0 + mtile * 16 + g * 4 + r] = part[r] * (1.0f / rsum[r]);
    }
  }
}

extern "C" void kernel_launch(void* const* d_in, const int* in_sizes, int n_in,
                              void* d_out, int out_size, void* d_ws, size_t ws_size,
                              hipStream_t stream) {
  const float* X  = (const float*)d_in[0];
  const float* W  = (const float*)d_in[1];
  const float* bs = (const float*)d_in[2];
  float* out = (float*)d_out;
  unsigned short* wf = (unsigned short*)d_ws;  // needs 224*208*2 = 93,184 B

  const int wtot = NKG * 8 * NPAD;
  hipLaunchKernelGGL(prep_w_kernel, dim3((wtot + 255) / 256), dim3(256), 0, stream,
                     W, wf);
  hipLaunchKernelGGL(attn_kernel, dim3(B_DIM * (D_DIM / DT)), dim3(256), 0, stream,
                     X, wf, bs, out);
}

// Round 3
// 347.479 us; speedup vs baseline: 1.0706x; 1.0706x over previous
//
#include <hip/hip_runtime.h>
#include <cstdint>
#include <cstddef>

#define B_DIM 512
#define T_DIM 200
#define D_DIM 512
#define NPAD  208   // N padded to 13*16
#define NKG   28    // K padded to 224 = 28 groups of 8
#define NT    13    // n-tiles of 16
#define DT    64    // d rows per block (was 128: 56KiB LDS -> 22% occ; 64 -> 28KiB -> ~50%)
#define KS_STEPS 7  // 224 / 32

typedef short  short8  __attribute__((ext_vector_type(8)));
typedef float  floatx4 __attribute__((ext_vector_type(4)));

__device__ __forceinline__ unsigned short f2bf(float f) {
  unsigned int u = __float_as_uint(f);
  u += 0x7fffu + ((u >> 16) & 1u);   // round-to-nearest-even
  return (unsigned short)(u >> 16);
}
__device__ __forceinline__ float bf2f(unsigned short h) {
  return __uint_as_float(((unsigned int)h) << 16);
}

// W (200x200 fp32) -> bf16, padded 224x208, B-fragment layout [k/8][n][k%8]
__global__ void prep_w_kernel(const float* __restrict__ W,
                              unsigned short* __restrict__ wf) {
  int idx = blockIdx.x * blockDim.x + threadIdx.x;
  if (idx >= NKG * 8 * NPAD) return;
  int k = idx / NPAD;
  int n = idx - k * NPAD;
  float v = (k < T_DIM && n < T_DIM) ? W[k * T_DIM + n] : 0.0f;
  wf[((size_t)(k >> 3) * NPAD + n) * 8 + (k & 7)] = f2bf(v);
}

__global__ __launch_bounds__(256, 4)
void attn_kernel(const float* __restrict__ X,
                 const unsigned short* __restrict__ wf,
                 const float* __restrict__ bias,
                 float* __restrict__ out) {
  // X tile in bf16, A-fragment layout [k/8][m][k%8]: 28*64*8*2B = 28 KiB
  __shared__ unsigned short Xa[NKG * DT * 8];

  const int tid = threadIdx.x;
  const int bb  = blockIdx.x >> 3;
  const int d0  = (blockIdx.x & 7) * DT;

  // ---- stage X tile: global fp32 (coalesced over d=m) -> LDS bf16 frag layout
  {
    const int m = tid & (DT - 1);
    const int q = tid >> 6;
    for (int kk = q; kk < NKG; kk += 4) {
      unsigned short pk[8];
      if (kk < 25) {  // T=200 = 25*8 exactly; kk>=25 is zero padding
        const float* g = X + ((size_t)bb * T_DIM + (size_t)kk * 8) * D_DIM + d0 + m;
        #pragma unroll
        for (int j = 0; j < 8; ++j) pk[j] = f2bf(g[(size_t)j * D_DIM]);
      } else {
        #pragma unroll
        for (int j = 0; j < 8; ++j) pk[j] = 0;
      }
      int4 w;
      w.x = (int)pk[0] | ((int)pk[1] << 16);
      w.y = (int)pk[2] | ((int)pk[3] << 16);
      w.z = (int)pk[4] | ((int)pk[5] << 16);
      w.w = (int)pk[6] | ((int)pk[7] << 16);
      *(int4*)(&Xa[(kk * DT + m) * 8]) = w;  // ds_write_b128
    }
  }
  __syncthreads();

  const int lane = tid & 63;
  const int l15  = lane & 15;
  const int g    = lane >> 4;
  const int wv   = tid >> 6;   // wave owns m-tile wv (16 d-rows)

  float bv[NT];
  #pragma unroll
  for (int nt = 0; nt < NT; ++nt) {
    int n = nt * 16 + l15;
    bv[nt] = (n < T_DIM) ? bias[n] : 0.0f;
  }

  floatx4 acc[NT];
  #pragma unroll
  for (int nt = 0; nt < NT; ++nt)
    acc[nt] = (floatx4){0.f, 0.f, 0.f, 0.f};

  // ---- K-loop: no barriers; B-frags stream from L2-resident wf
  for (int ks = 0; ks < KS_STEPS; ++ks) {
    const int kg = ks * 4 + g;
    short8 a = *(const short8*)(&Xa[(kg * DT + wv * 16 + l15) * 8]);
    const unsigned short* wp = wf + ((size_t)kg * NPAD + l15) * 8;
    #pragma unroll
    for (int nt = 0; nt < NT; ++nt) {
      short8 bfr = *(const short8*)(wp + nt * 16 * 8);
      acc[nt] = __builtin_amdgcn_mfma_f32_16x16x32_bf16(a, bfr, acc[nt], 0, 0, 0);
    }
  }

  // ---- fused epilogue: p = exp(tanh(z)); softmax needs NO max pass since
  // tanh is bounded in [-1,1] (exp in [0.37,2.72], sum in [73,544] -> stable).
  // C/D layout: col = lane&15 (n = t), row = g*4 + r (m within tile).
  float part[4] = {0.f, 0.f, 0.f, 0.f};
  float rs[4]   = {0.f, 0.f, 0.f, 0.f};
  #pragma unroll
  for (int nt = 0; nt < NT; ++nt) {
    const int t = nt * 16 + l15;
    const bool valid = (t < T_DIM);
    const unsigned short* xp = &Xa[((t >> 3) * DT) * 8 + (t & 7)];
    #pragma unroll
    for (int r = 0; r < 4; ++r) {
      if (valid) {
        float z  = acc[nt][r] + bv[nt];
        float e  = __expf(2.0f * z);              // tanh = 1 - 2/(e^{2z}+1)
        float th = 1.0f - __fdividef(2.0f, e + 1.0f);
        float p  = __expf(th);
        rs[r]   += p;
        const int m = wv * 16 + g * 4 + r;
        part[r] += p * bf2f(xp[m * 8]);           // X[t][d0+m]
      }
    }
  }
  // reduce over the 16 t-lanes only (each (g,r) is a distinct output row)
  #pragma unroll
  for (int off = 1; off <= 8; off <<= 1)
    #pragma unroll
    for (int r = 0; r < 4; ++r) {
      part[r] += __shfl_xor(part[r], off, 16);
      rs[r]   += __shfl_xor(rs[r],   off, 16);
    }

  if (l15 == 0) {
    #pragma unroll
    for (int r = 0; r < 4; ++r)
      out[(size_t)bb * D_DIM + d0 + wv * 16 + g * 4 + r] = part[r] * __frcp_rn(rs[r]);
  }
}

extern "C" void kernel_launch(void* const* d_in, const int* in_sizes, int n_in,
                              void* d_out, int out_size, void* d_ws, size_t ws_size,
                              hipStream_t stream) {
  const float* X  = (const float*)d_in[0];
  const float* W  = (const float*)d_in[1];
  const float* bs = (const float*)d_in[2];
  float* out = (float*)d_out;
  unsigned short* wf = (unsigned short*)d_ws;  // needs 224*208*2 = 93,184 B

  const int wtot = NKG * 8 * NPAD;
  hipLaunchKernelGGL(prep_w_kernel, dim3((wtot + 255) / 256), dim3(256), 0, stream,
                     W, wf);
  hipLaunchKernelGGL(attn_kernel, dim3(B_DIM * (D_DIM / DT)), dim3(256), 0, stream,
                     X, wf, bs, out);
}